// Round 5
// baseline (303.195 us; speedup 1.0000x reference)
//
#include <hip/hip_runtime.h>
#include <hip/hip_fp16.h>

// Arena-contiguous scatter/gather, v4 (full-occupancy fill):
//   ws budget forces K=2 (arena for all 4M records = 32MB > ws). Per chunk:
//   count : 96 blocks; per-block LDS histogram -> plain-store rows (aliased
//           into arena head, consumed by scan before fill overwrites).
//   scan  : 1 block; column-reduce rows, block scan -> base[NB+1]; init
//           padded cursors; zero accSlots on first chunk.
//   fill  : tile = 2048 elems (489 blocks/chunk -> ~1.9 blocks/CU, machine
//           FULL; v3 used 4096-elem tiles -> 245 blocks = half idle).
//           ONE-stage LDS bucket sort: hist atomics -> single packed scan ->
//           scatter into 32KB slab -> coalesced flush into the bucket's
//           contiguous arena range (astart from one cursor fetch_add).
//   accum : block = bucket; dense coalesced read of its arena range into an
//           LDS fp32 tile (+fp32 partial across chunks); fused loss on last.
//   final : 1 wave reduces 64 slot pairs, divides, writes out[0].
// Records: 8B {fx16,fy16 | local16,fz16}.

#define SPAN   1024
#define NBMAX  1024
#define CURP   16            // ints per padded cursor slot (64 B line)
#define FTH    1024          // fill threads
#define FBE    2048          // elems per fill tile (4096 records = one slab)
#define ATH    512           // accum threads
#define CB     96            // count blocks (plain-store rows)

struct F3 { float x, y, z; };

__device__ __forceinline__ uint2 packrec(float fx, float fy, float fz, int local) {
    unsigned short hx = __half_as_ushort(__float2half(fx));
    unsigned short hy = __half_as_ushort(__float2half(fy));
    unsigned short hz = __half_as_ushort(__float2half(fz));
    return make_uint2(((unsigned)hy << 16) | hx, ((unsigned)local << 16) | hz);
}

// 1024-thread inclusive scan. Call sites must be separated by __syncthreads().
__device__ __forceinline__ int block_incl_scan(int v, int* wsum, int lane, int wv) {
    #pragma unroll
    for (int off = 1; off < 64; off <<= 1) {
        int t = __shfl_up(v, off, 64);
        if (lane >= off) v += t;
    }
    if (lane == 63) wsum[wv] = v;
    __syncthreads();
    if (wv == 0) {
        int w = (lane < 16) ? wsum[lane] : 0;
        #pragma unroll
        for (int off = 1; off < 16; off <<= 1) {
            int t = __shfl_up(w, off, 64);
            if (lane >= off) w += t;
        }
        if (lane < 16) wsum[lane] = w;
    }
    __syncthreads();
    return v + ((wv > 0) ? wsum[wv - 1] : 0);
}

__global__ void __launch_bounds__(1024)
count_kernel(const long long* __restrict__ conn, int* __restrict__ rows,
             int cs, int ce) {
    __shared__ int h[NBMAX];
    int tid = threadIdx.x;
    h[tid] = 0;
    __syncthreads();
    int stride = gridDim.x * 1024;
    for (int e = cs + blockIdx.x * 1024 + tid; e < ce; e += stride) {
        long long v = __builtin_nontemporal_load(conn + e);
        int na = (int)(unsigned)((unsigned long long)v & 0xFFFFFFFFull);
        int nb = (int)(unsigned)((unsigned long long)v >> 32);
        atomicAdd(&h[na >> 10], 1);
        atomicAdd(&h[nb >> 10], 1);
    }
    __syncthreads();
    rows[blockIdx.x * NBMAX + tid] = h[tid];   // plain store, no zero needed
}

__global__ void __launch_bounds__(1024)
scan_kernel(const int* __restrict__ rows, int* __restrict__ cursor,
            int* __restrict__ base, double* __restrict__ accSlots,
            int isFirst) {
    __shared__ int wsum[16];
    int tid = threadIdx.x, lane = tid & 63, wv = tid >> 6;
    int c = 0;
    #pragma unroll 4
    for (int r = 0; r < CB; ++r) c += rows[r * NBMAX + tid];  // coalesced cols
    int incl = block_incl_scan(c, wsum, lane, wv);
    base[tid + 1] = incl;
    if (tid == 0) base[0] = 0;
    cursor[tid * CURP] = incl - c;   // cursor = exclusive start
    if (isFirst && tid < 512) accSlots[tid] = 0.0;
}

__global__ void __launch_bounds__(1024)
fill_kernel(const long long* __restrict__ conn,
            const F3*  __restrict__ pred,
            const float* __restrict__ u_c,
            const float* __restrict__ theta_c,
            const float* __restrict__ len,
            const float* __restrict__ pE,
            const float* __restrict__ pA,
            const float* __restrict__ pI,
            const float* __restrict__ dir,
            uint2* __restrict__ arena,
            int* __restrict__ cursor,
            int cs, int ce) {
    __shared__ uint2          slab[2 * FBE];   // 4096 recs, 32KB
    __shared__ unsigned short sbk [2 * FBE];   // 8KB
    __shared__ int hist [NBMAX];               // 4KB
    __shared__ int boff [NBMAX];               // 4KB  block-local bucket start
    __shared__ int astart[NBMAX];              // 4KB  arena start per bucket
    __shared__ int wsum [16];
    // total 53,312 B -> 2 blocks/CU (thread-capped), 32 waves/CU

    int tid = threadIdx.x, lane = tid & 63, wv = tid >> 6;

    hist[tid] = 0;
    __syncthreads();

    float uc = u_c[0];
    float tc = theta_c[0];
    int bs = cs + blockIdx.x * FBE;
    int be = bs + FBE; if (be > ce) be = ce;

    unsigned sv[4];   // (rank<<10)|bucket ; 0xFFFFFFFF = none
    uint2    rc[4];

    #pragma unroll
    for (int j = 0; j < 2; ++j) {
        int e = bs + j * FTH + tid;
        unsigned sa = 0xFFFFFFFFu, sb = 0xFFFFFFFFu;
        if (e < be) {
            long long cv = __builtin_nontemporal_load(conn + e);
            int na = (int)(unsigned)((unsigned long long)cv & 0xFFFFFFFFull);
            int nb = (int)(unsigned)((unsigned long long)cv >> 32);

            F3 pa_ = pred[na];            // temporal: keep L2/L3-resident
            F3 pb_ = pred[nb];

            float c  = __builtin_nontemporal_load(&dir[3 * e + 0]);
            float s  = __builtin_nontemporal_load(&dir[3 * e + 2]);
            float L  = __builtin_nontemporal_load(&len[e]);
            float Ee = __builtin_nontemporal_load(&pE[e]);
            float EA = Ee * __builtin_nontemporal_load(&pA[e]);
            float EI = Ee * __builtin_nontemporal_load(&pI[e]);

            float a0 = pa_.x * uc;
            float a1 = pa_.y * uc;
            float a2 = pa_.z * tc;
            float b0 = pb_.x * uc;
            float b1 = pb_.y * uc;
            float b2 = pb_.z * tc;

            float u_A  =  c * a0 + s * a1;
            float w_A  = -s * a0 + c * a1;
            float th_A = -a2;
            float u_B  =  c * b0 + s * b1;
            float w_B  = -s * b0 + c * b1;
            float th_B = -b2;

            float invL  = 1.0f / L;
            float ea_l  = EA * invL;             // AXIAL_WEIGHT = 1.0
            float ei_l  = EI * invL;
            float ei_l2 = ei_l  * invL;
            float ei_l3 = ei_l2 * invL;

            float dw = w_A - w_B;
            float f0 = ea_l * (u_A - u_B);
            float f1 = 12.0f * ei_l3 * dw + 6.0f * ei_l2 * (th_A + th_B);
            float f2 = 6.0f * ei_l2 * dw + 4.0f * ei_l * th_A + 2.0f * ei_l * th_B;
            float f5 = 6.0f * ei_l2 * dw + 2.0f * ei_l * th_A + 4.0f * ei_l * th_B;

            float fA0 = c * f0 - s * f1;
            float fA1 = s * f0 + c * f1;

            int bkA = na >> 10;
            int rA  = atomicAdd(&hist[bkA], 1);
            sa = ((unsigned)rA << 10) | (unsigned)bkA;
            rc[2 * j + 0] = packrec(fA0, fA1, -f2, na & 1023);

            int bkB = nb >> 10;
            int rB  = atomicAdd(&hist[bkB], 1);
            sb = ((unsigned)rB << 10) | (unsigned)bkB;
            rc[2 * j + 1] = packrec(-fA0, -fA1, -f5, nb & 1023);
        }
        sv[2 * j + 0] = sa;
        sv[2 * j + 1] = sb;
    }
    __syncthreads();

    // one arena reservation per (tile,bucket); single scan gives local layout
    int h = hist[tid];
    if (h) astart[tid] = atomicAdd(&cursor[tid * CURP], h);
    int iT = block_incl_scan(h, wsum, lane, wv);   // internal syncs order astart
    boff[tid] = iT - h;
    __syncthreads();

    // scatter into slab, sorted by bucket
    #pragma unroll
    for (int r = 0; r < 4; ++r) {
        unsigned s2 = sv[r];
        if (s2 != 0xFFFFFFFFu) {
            int bk = (int)(s2 & 1023u);
            int rk = (int)(s2 >> 10);
            int slot = boff[bk] + rk;
            slab[slot] = rc[r];
            sbk[slot]  = (unsigned short)bk;
        }
    }
    __syncthreads();

    // coalesced flush: bucket runs are contiguous in both slab and arena
    int tot = boff[NBMAX - 1] + hist[NBMAX - 1];
    for (int i = tid; i < tot; i += FTH) {
        int bk = sbk[i];
        arena[astart[bk] + (i - boff[bk])] = slab[i];
    }
}

__global__ void __launch_bounds__(512)
accum_kernel(const unsigned long long* __restrict__ arena,
             const int* __restrict__ base,
             const float* __restrict__ Fext,
             const float* __restrict__ bcd,
             const float* __restrict__ bcr,
             double* __restrict__ accSlots,
             float* __restrict__ fint32,
             __half* __restrict__ fint16,
             int N, int isFirst, int isLast, int mode) {
    __shared__ float tile[SPAN * 3];
    __shared__ double sn[8], sd[8];

    int tid = threadIdx.x, lane = tid & 63, wv = tid >> 6;
    int b = blockIdx.x;
    int nodeLo = b * SPAN;
    int gBase = nodeLo * 3;
    int gMax  = 3 * N;

    if (isFirst) {
        for (int i = tid; i < SPAN * 3; i += ATH) tile[i] = 0.0f;
    } else if (mode == 1) {
        for (int i = tid; i < SPAN * 3; i += ATH) {
            int g = gBase + i;
            tile[i] = (g < gMax) ? fint32[g] : 0.0f;
        }
    } else {
        for (int i = tid; i < SPAN * 3; i += ATH) {
            int g = gBase + i;
            tile[i] = (g < gMax) ? __half2float(fint16[g]) : 0.0f;
        }
    }
    __syncthreads();

    // dense coalesced replay of this bucket's contiguous arena range
    int s0 = base[b];
    int s1 = base[b + 1];
    for (int i = s0 + tid; i < s1; i += ATH) {
        unsigned long long rv = __builtin_nontemporal_load(arena + i);
        unsigned lo = (unsigned)(rv & 0xFFFFFFFFull);
        unsigned hi = (unsigned)(rv >> 32);
        float fx = __half2float(__ushort_as_half((unsigned short)(lo & 0xFFFFu)));
        float fy = __half2float(__ushort_as_half((unsigned short)(lo >> 16)));
        float fz = __half2float(__ushort_as_half((unsigned short)(hi & 0xFFFFu)));
        int local = (int)(hi >> 16);
        atomicAdd(&tile[local * 3 + 0], fx);
        atomicAdd(&tile[local * 3 + 1], fy);
        atomicAdd(&tile[local * 3 + 2], fz);
    }
    __syncthreads();

    if (!isLast) {
        if (mode == 1) {
            for (int i = tid; i < SPAN * 3; i += ATH) {
                int g = gBase + i;
                if (g < gMax) fint32[g] = tile[i];
            }
        } else {
            for (int i = tid; i < SPAN * 3; i += ATH) {
                int g = gBase + i;
                if (g < gMax) fint16[g] = __float2half(tile[i]);
            }
        }
        return;
    }

    // fused masked loss over this bucket's node range
    int spanCnt = N - nodeLo;
    if (spanCnt > SPAN) spanCnt = SPAN;

    double num = 0.0, den = 0.0;
    for (int l = tid; l < spanCnt; l += ATH) {
        int n = nodeLo + l;
        float md = 1.0f - __builtin_nontemporal_load(&bcd[n]);
        float mr = 1.0f - __builtin_nontemporal_load(&bcr[n]);
        float e0 = __builtin_nontemporal_load(&Fext[3 * n + 0]);
        float e1 = __builtin_nontemporal_load(&Fext[3 * n + 1]);
        float e2 = __builtin_nontemporal_load(&Fext[3 * n + 2]);
        float r0 = (tile[l * 3 + 0] - e0) * md;
        float r1 = (tile[l * 3 + 1] - e1) * md;
        float r2 = (tile[l * 3 + 2] - e2) * mr;
        float g0 = e0 * md;
        float g1 = e1 * md;
        float g2 = e2 * mr;
        num += (double)r0 * r0 + (double)r1 * r1 + (double)r2 * r2;
        den += (double)g0 * g0 + (double)g1 * g1 + (double)g2 * g2;
    }
    #pragma unroll
    for (int off = 32; off > 0; off >>= 1) {
        num += __shfl_down(num, off, 64);
        den += __shfl_down(den, off, 64);
    }
    if (lane == 0) { sn[wv] = num; sd[wv] = den; }
    __syncthreads();
    if (tid == 0) {
        double tn = 0.0, td = 0.0;
        #pragma unroll
        for (int w = 0; w < 8; ++w) { tn += sn[w]; td += sd[w]; }
        double* slot = accSlots + (size_t)(b & 63) * 8;
        atomicAdd(&slot[0], tn);
        atomicAdd(&slot[1], td);
    }
}

__global__ void final_kernel(const double* __restrict__ accSlots,
                             float* __restrict__ out) {
    int t = threadIdx.x;   // 64 threads
    double n = accSlots[t * 8 + 0];
    double d = accSlots[t * 8 + 1];
    #pragma unroll
    for (int off = 32; off > 0; off >>= 1) {
        n += __shfl_down(n, off, 64);
        d += __shfl_down(d, off, 64);
    }
    if (t == 0) {
        if (d < 1e-30) d = 1e-30;
        out[0] = (float)(n / d);
    }
}

static inline size_t align256(size_t x) { return (x + 255) & ~(size_t)255; }

extern "C" void kernel_launch(void* const* d_in, const int* in_sizes, int n_in,
                              void* d_out, int out_size, void* d_ws, size_t ws_size,
                              hipStream_t stream) {
    const F3*    pred    = (const F3*)d_in[0];
    const float* u_c     = (const float*)d_in[1];
    const float* theta_c = (const float*)d_in[2];
    const float* len     = (const float*)d_in[3];
    const float* pE      = (const float*)d_in[4];
    const float* pA      = (const float*)d_in[5];
    const float* pI      = (const float*)d_in[6];
    const float* dir     = (const float*)d_in[7];
    const float* Fext    = (const float*)d_in[8];
    const float* bcd     = (const float*)d_in[9];
    const float* bcr     = (const float*)d_in[10];
    const long long* conn = (const long long*)d_in[11];

    int N = in_sizes[0] / 3;
    int E = in_sizes[3];
    int NB = (N + SPAN - 1) / SPAN;   // must be <= NBMAX

    // Workspace layout:
    //   0      accSlots   4096 B (64 slots * 64B)
    //   4096   cursors    NBMAX*CURP*4 = 65536 B (padded, one cursor/line)
    //   69632  base       (NBMAX+1)*4 B
    //   oFint  fp32/fp16 partial (K>1 only)
    //   oArena arena: 2*chunkElems records * 8 B (exact); the count-row
    //          matrix cntMat[CB][NBMAX] (384 KB) ALIASES the arena head —
    //          it is consumed by scan before fill writes the arena.
    size_t oCur   = 4096;
    size_t oBase  = oCur + (size_t)NBMAX * CURP * 4;          // 69632
    size_t oFint0 = align256(oBase + 4 * (NBMAX + 1));        // 73984
    size_t rowsBytes = (size_t)CB * NBMAX * 4;                // 393216

    const int cfgK[6] = {1, 2, 2, 4, 4, 8};
    const int cfgM[6] = {0, 1, 2, 1, 2, 2};
    int K = 8, mode = 2;
    size_t oF = oFint0, oA = oFint0;
    for (int t = 0; t < 6; ++t) {
        int Kc = cfgK[t], Mc = cfgM[t];
        size_t chunkE = (size_t)(E + Kc - 1) / Kc;
        size_t fsz = (Kc > 1) ? (size_t)3 * N * (Mc == 1 ? 4 : 2) : 0;
        size_t oAt = align256(oFint0 + fsz);
        size_t arenaB = 2 * chunkE * 8;
        if (arenaB < rowsBytes) arenaB = rowsBytes;   // alias safety for tiny E
        size_t need = oAt + arenaB;
        if (need <= ws_size || t == 5) {
            K = Kc; mode = Mc; oF = oFint0; oA = oAt;
            if (need <= ws_size) break;
        }
    }

    int chunkElems = (E + K - 1) / K;

    double*             accSlots = (double*)d_ws;
    int*                cursor   = (int*)((char*)d_ws + oCur);
    int*                base     = (int*)((char*)d_ws + oBase);
    float*              fint32   = (float*)((char*)d_ws + oF);
    __half*             fint16   = (__half*)((char*)d_ws + oF);
    uint2*              arena    = (uint2*)((char*)d_ws + oA);
    unsigned long long* arenaLL  = (unsigned long long*)arena;
    int*                rows     = (int*)arena;       // alias, pre-fill only

    for (int c = 0; c < K; ++c) {
        int cs = c * chunkElems;
        if (cs >= E) break;
        int ce = cs + chunkElems;
        if (ce > E) ce = E;
        int NT = (ce - cs + FBE - 1) / FBE;

        int isFirst = (c == 0);
        int isLast  = (ce == E);

        count_kernel<<<CB, 1024, 0, stream>>>(conn, rows, cs, ce);
        scan_kernel<<<1, 1024, 0, stream>>>(rows, cursor, base, accSlots, isFirst);
        fill_kernel<<<NT, FTH, 0, stream>>>(
            conn, pred, u_c, theta_c, len, pE, pA, pI, dir,
            arena, cursor, cs, ce);
        accum_kernel<<<NB, ATH, 0, stream>>>(
            arenaLL, base, Fext, bcd, bcr, accSlots,
            fint32, fint16, N, isFirst, isLast, mode);
    }

    final_kernel<<<1, 64, 0, stream>>>(accSlots, (float*)d_out);
}

// Round 6
// 278.703 us; speedup vs baseline: 1.0879x; 1.0879x over previous
//
#include <hip/hip_runtime.h>
#include <hip/hip_fp16.h>

// Arena-contiguous scatter/gather, v5 (coarse buckets = coalesced arena runs):
//   Buckets are now 4096 nodes (256 max). Per-tile-per-bucket arena runs are
//   ~16 records (133 B) instead of 4 (32 B) -> full-sector writes, no RMW.
//   count : 96 blocks; per-block LDS histogram (256 slots) -> plain-store rows
//           (aliased into arena head, consumed by scan before fill writes).
//   scan  : 1 block; column-reduce rows, block scan -> base[NBC+1]; init
//           padded cursors; zero accSlots on first chunk.
//   fill  : tile = 2048 elems (489 blocks/chunk, ~1.9/CU). ONE-stage LDS
//           bucket sort (hist -> scan -> scatter 32KB slab) -> coalesced
//           flush into the bucket's contiguous arena range.
//   accum : block = coarse bucket (245 blocks, 1024 thr, 48KB fp32 tile);
//           dense coalesced arena stream; fp32 partial across chunks;
//           fused masked loss on last chunk.
//   final : 1 wave reduces 64 slot pairs, divides, writes out[0].
// Records: 8B {fx16,fy16 | local12,fz16}. ws: K=2/fp32 = ~28.0 MB.

#define SPANC  4096          // nodes per coarse bucket
#define NBC    256           // max coarse buckets
#define CURP   16            // ints per padded cursor slot (64 B line)
#define FTH    1024          // fill threads
#define FBE    2048          // elems per fill tile (4096 records = one slab)
#define ATH    1024          // accum threads
#define CB     96            // count blocks (plain-store rows)

struct F3 { float x, y, z; };

__device__ __forceinline__ uint2 packrec(float fx, float fy, float fz, int local) {
    unsigned short hx = __half_as_ushort(__float2half(fx));
    unsigned short hy = __half_as_ushort(__float2half(fy));
    unsigned short hz = __half_as_ushort(__float2half(fz));
    return make_uint2(((unsigned)hy << 16) | hx, ((unsigned)local << 16) | hz);
}

// 1024-thread inclusive scan. Call sites must be separated by __syncthreads().
__device__ __forceinline__ int block_incl_scan(int v, int* wsum, int lane, int wv) {
    #pragma unroll
    for (int off = 1; off < 64; off <<= 1) {
        int t = __shfl_up(v, off, 64);
        if (lane >= off) v += t;
    }
    if (lane == 63) wsum[wv] = v;
    __syncthreads();
    if (wv == 0) {
        int w = (lane < 16) ? wsum[lane] : 0;
        #pragma unroll
        for (int off = 1; off < 16; off <<= 1) {
            int t = __shfl_up(w, off, 64);
            if (lane >= off) w += t;
        }
        if (lane < 16) wsum[lane] = w;
    }
    __syncthreads();
    return v + ((wv > 0) ? wsum[wv - 1] : 0);
}

__global__ void __launch_bounds__(1024)
count_kernel(const long long* __restrict__ conn, int* __restrict__ rows,
             int cs, int ce) {
    __shared__ int h[NBC];
    int tid = threadIdx.x;
    if (tid < NBC) h[tid] = 0;
    __syncthreads();
    int stride = gridDim.x * 1024;
    for (int e = cs + blockIdx.x * 1024 + tid; e < ce; e += stride) {
        long long v = __builtin_nontemporal_load(conn + e);
        int na = (int)(unsigned)((unsigned long long)v & 0xFFFFFFFFull);
        int nb = (int)(unsigned)((unsigned long long)v >> 32);
        atomicAdd(&h[na >> 12], 1);
        atomicAdd(&h[nb >> 12], 1);
    }
    __syncthreads();
    if (tid < NBC) rows[blockIdx.x * NBC + tid] = h[tid];   // plain store
}

__global__ void __launch_bounds__(1024)
scan_kernel(const int* __restrict__ rows, int* __restrict__ cursor,
            int* __restrict__ base, double* __restrict__ accSlots,
            int isFirst) {
    __shared__ int wsum[16];
    int tid = threadIdx.x, lane = tid & 63, wv = tid >> 6;
    int c = 0;
    if (tid < NBC) {
        #pragma unroll 4
        for (int r = 0; r < CB; ++r) c += rows[r * NBC + tid];
    }
    int incl = block_incl_scan(c, wsum, lane, wv);
    if (tid < NBC) {
        base[tid + 1] = incl;
        cursor[tid * CURP] = incl - c;   // cursor = exclusive start
    }
    if (tid == 0) base[0] = 0;
    if (isFirst && tid < 512) accSlots[tid] = 0.0;
}

__global__ void __launch_bounds__(1024)
fill_kernel(const long long* __restrict__ conn,
            const F3*  __restrict__ pred,
            const float* __restrict__ u_c,
            const float* __restrict__ theta_c,
            const float* __restrict__ len,
            const float* __restrict__ pE,
            const float* __restrict__ pA,
            const float* __restrict__ pI,
            const float* __restrict__ dir,
            uint2* __restrict__ arena,
            int* __restrict__ cursor,
            int cs, int ce) {
    __shared__ uint2         slab[2 * FBE];   // 4096 recs, 32KB
    __shared__ unsigned char sbk [2 * FBE];   // 4KB (bucket < 256)
    __shared__ int hist [NBC];                // 1KB
    __shared__ int boff [NBC];                // 1KB  block-local bucket start
    __shared__ int astart[NBC];               // 1KB  arena start per bucket
    __shared__ int wsum [16];
    // total ~39.3KB -> 2 blocks/CU (thread-capped), 32 waves/CU

    int tid = threadIdx.x, lane = tid & 63, wv = tid >> 6;

    if (tid < NBC) hist[tid] = 0;
    __syncthreads();

    float uc = u_c[0];
    float tc = theta_c[0];
    int bs = cs + blockIdx.x * FBE;
    int be = bs + FBE; if (be > ce) be = ce;

    unsigned sv[4];   // (rank<<8)|bucket ; 0xFFFFFFFF = none
    uint2    rc[4];

    #pragma unroll
    for (int j = 0; j < 2; ++j) {
        int e = bs + j * FTH + tid;
        unsigned sa = 0xFFFFFFFFu, sb = 0xFFFFFFFFu;
        if (e < be) {
            long long cv = __builtin_nontemporal_load(conn + e);
            int na = (int)(unsigned)((unsigned long long)cv & 0xFFFFFFFFull);
            int nb = (int)(unsigned)((unsigned long long)cv >> 32);

            F3 pa_ = pred[na];            // temporal: keep cache-resident
            F3 pb_ = pred[nb];

            float c  = __builtin_nontemporal_load(&dir[3 * e + 0]);
            float s  = __builtin_nontemporal_load(&dir[3 * e + 2]);
            float L  = __builtin_nontemporal_load(&len[e]);
            float Ee = __builtin_nontemporal_load(&pE[e]);
            float EA = Ee * __builtin_nontemporal_load(&pA[e]);
            float EI = Ee * __builtin_nontemporal_load(&pI[e]);

            float a0 = pa_.x * uc;
            float a1 = pa_.y * uc;
            float a2 = pa_.z * tc;
            float b0 = pb_.x * uc;
            float b1 = pb_.y * uc;
            float b2 = pb_.z * tc;

            float u_A  =  c * a0 + s * a1;
            float w_A  = -s * a0 + c * a1;
            float th_A = -a2;
            float u_B  =  c * b0 + s * b1;
            float w_B  = -s * b0 + c * b1;
            float th_B = -b2;

            float invL  = 1.0f / L;
            float ea_l  = EA * invL;             // AXIAL_WEIGHT = 1.0
            float ei_l  = EI * invL;
            float ei_l2 = ei_l  * invL;
            float ei_l3 = ei_l2 * invL;

            float dw = w_A - w_B;
            float f0 = ea_l * (u_A - u_B);
            float f1 = 12.0f * ei_l3 * dw + 6.0f * ei_l2 * (th_A + th_B);
            float f2 = 6.0f * ei_l2 * dw + 4.0f * ei_l * th_A + 2.0f * ei_l * th_B;
            float f5 = 6.0f * ei_l2 * dw + 2.0f * ei_l * th_A + 4.0f * ei_l * th_B;

            float fA0 = c * f0 - s * f1;
            float fA1 = s * f0 + c * f1;

            int bkA = na >> 12;
            int rA  = atomicAdd(&hist[bkA], 1);
            sa = ((unsigned)rA << 8) | (unsigned)bkA;
            rc[2 * j + 0] = packrec(fA0, fA1, -f2, na & 4095);

            int bkB = nb >> 12;
            int rB  = atomicAdd(&hist[bkB], 1);
            sb = ((unsigned)rB << 8) | (unsigned)bkB;
            rc[2 * j + 1] = packrec(-fA0, -fA1, -f5, nb & 4095);
        }
        sv[2 * j + 0] = sa;
        sv[2 * j + 1] = sb;
    }
    __syncthreads();

    // one arena reservation per (tile,bucket); single scan gives local layout
    int h = (tid < NBC) ? hist[tid] : 0;
    if (tid < NBC && h) astart[tid] = atomicAdd(&cursor[tid * CURP], h);
    int iT = block_incl_scan(h, wsum, lane, wv);   // internal syncs order astart
    if (tid < NBC) boff[tid] = iT - h;
    __syncthreads();

    // scatter into slab, sorted by bucket
    #pragma unroll
    for (int r = 0; r < 4; ++r) {
        unsigned s2 = sv[r];
        if (s2 != 0xFFFFFFFFu) {
            int bk = (int)(s2 & 255u);
            int rk = (int)(s2 >> 8);
            int slot = boff[bk] + rk;
            slab[slot] = rc[r];
            sbk[slot]  = (unsigned char)bk;
        }
    }
    __syncthreads();

    // coalesced flush: ~16-record runs contiguous in both slab and arena
    int tot = boff[NBC - 1] + hist[NBC - 1];
    for (int i = tid; i < tot; i += FTH) {
        int bk = sbk[i];
        arena[astart[bk] + (i - boff[bk])] = slab[i];
    }
}

__global__ void __launch_bounds__(1024)
accum_kernel(const unsigned long long* __restrict__ arena,
             const int* __restrict__ base,
             const float* __restrict__ Fext,
             const float* __restrict__ bcd,
             const float* __restrict__ bcr,
             double* __restrict__ accSlots,
             float* __restrict__ fint32,
             __half* __restrict__ fint16,
             int N, int isFirst, int isLast, int mode) {
    __shared__ float tile[SPANC * 3];   // 48KB
    __shared__ double sn[16], sd[16];

    int tid = threadIdx.x, lane = tid & 63, wv = tid >> 6;
    int b = blockIdx.x;
    int nodeLo = b * SPANC;
    int gBase = nodeLo * 3;
    int gMax  = 3 * N;

    if (isFirst) {
        for (int i = tid; i < SPANC * 3; i += ATH) tile[i] = 0.0f;
    } else if (mode == 1) {
        for (int i = tid; i < SPANC * 3; i += ATH) {
            int g = gBase + i;
            tile[i] = (g < gMax) ? fint32[g] : 0.0f;
        }
    } else {
        for (int i = tid; i < SPANC * 3; i += ATH) {
            int g = gBase + i;
            tile[i] = (g < gMax) ? __half2float(fint16[g]) : 0.0f;
        }
    }
    __syncthreads();

    // dense coalesced replay of this bucket's contiguous arena range
    int s0 = base[b];
    int s1 = base[b + 1];
    for (int i = s0 + tid; i < s1; i += ATH) {
        unsigned long long rv = __builtin_nontemporal_load(arena + i);
        unsigned lo = (unsigned)(rv & 0xFFFFFFFFull);
        unsigned hi = (unsigned)(rv >> 32);
        float fx = __half2float(__ushort_as_half((unsigned short)(lo & 0xFFFFu)));
        float fy = __half2float(__ushort_as_half((unsigned short)(lo >> 16)));
        float fz = __half2float(__ushort_as_half((unsigned short)(hi & 0xFFFFu)));
        int local = (int)(hi >> 16);
        atomicAdd(&tile[local * 3 + 0], fx);
        atomicAdd(&tile[local * 3 + 1], fy);
        atomicAdd(&tile[local * 3 + 2], fz);
    }
    __syncthreads();

    if (!isLast) {
        if (mode == 1) {
            for (int i = tid; i < SPANC * 3; i += ATH) {
                int g = gBase + i;
                if (g < gMax) fint32[g] = tile[i];
            }
        } else {
            for (int i = tid; i < SPANC * 3; i += ATH) {
                int g = gBase + i;
                if (g < gMax) fint16[g] = __float2half(tile[i]);
            }
        }
        return;
    }

    // fused masked loss over this bucket's node range
    int spanCnt = N - nodeLo;
    if (spanCnt > SPANC) spanCnt = SPANC;

    double num = 0.0, den = 0.0;
    for (int l = tid; l < spanCnt; l += ATH) {
        int n = nodeLo + l;
        float md = 1.0f - __builtin_nontemporal_load(&bcd[n]);
        float mr = 1.0f - __builtin_nontemporal_load(&bcr[n]);
        float e0 = __builtin_nontemporal_load(&Fext[3 * n + 0]);
        float e1 = __builtin_nontemporal_load(&Fext[3 * n + 1]);
        float e2 = __builtin_nontemporal_load(&Fext[3 * n + 2]);
        float r0 = (tile[l * 3 + 0] - e0) * md;
        float r1 = (tile[l * 3 + 1] - e1) * md;
        float r2 = (tile[l * 3 + 2] - e2) * mr;
        float g0 = e0 * md;
        float g1 = e1 * md;
        float g2 = e2 * mr;
        num += (double)r0 * r0 + (double)r1 * r1 + (double)r2 * r2;
        den += (double)g0 * g0 + (double)g1 * g1 + (double)g2 * g2;
    }
    #pragma unroll
    for (int off = 32; off > 0; off >>= 1) {
        num += __shfl_down(num, off, 64);
        den += __shfl_down(den, off, 64);
    }
    if (lane == 0) { sn[wv] = num; sd[wv] = den; }
    __syncthreads();
    if (tid == 0) {
        double tn = 0.0, td = 0.0;
        #pragma unroll
        for (int w = 0; w < 16; ++w) { tn += sn[w]; td += sd[w]; }
        double* slot = accSlots + (size_t)(b & 63) * 8;
        atomicAdd(&slot[0], tn);
        atomicAdd(&slot[1], td);
    }
}

__global__ void final_kernel(const double* __restrict__ accSlots,
                             float* __restrict__ out) {
    int t = threadIdx.x;   // 64 threads
    double n = accSlots[t * 8 + 0];
    double d = accSlots[t * 8 + 1];
    #pragma unroll
    for (int off = 32; off > 0; off >>= 1) {
        n += __shfl_down(n, off, 64);
        d += __shfl_down(d, off, 64);
    }
    if (t == 0) {
        if (d < 1e-30) d = 1e-30;
        out[0] = (float)(n / d);
    }
}

static inline size_t align256(size_t x) { return (x + 255) & ~(size_t)255; }

extern "C" void kernel_launch(void* const* d_in, const int* in_sizes, int n_in,
                              void* d_out, int out_size, void* d_ws, size_t ws_size,
                              hipStream_t stream) {
    const F3*    pred    = (const F3*)d_in[0];
    const float* u_c     = (const float*)d_in[1];
    const float* theta_c = (const float*)d_in[2];
    const float* len     = (const float*)d_in[3];
    const float* pE      = (const float*)d_in[4];
    const float* pA      = (const float*)d_in[5];
    const float* pI      = (const float*)d_in[6];
    const float* dir     = (const float*)d_in[7];
    const float* Fext    = (const float*)d_in[8];
    const float* bcd     = (const float*)d_in[9];
    const float* bcr     = (const float*)d_in[10];
    const long long* conn = (const long long*)d_in[11];

    int N = in_sizes[0] / 3;
    int E = in_sizes[3];
    int NBc = (N + SPANC - 1) / SPANC;   // coarse buckets, must be <= NBC

    // Workspace layout:
    //   0      accSlots   4096 B (64 slots * 64B)
    //   4096   cursors    NBC*CURP*4 = 16384 B (padded, one cursor/line)
    //   20480  base       (NBC+1)*4 B
    //   oFint  fp32/fp16 partial (K>1 only)
    //   oArena arena: 2*chunkElems records * 8 B (exact); the count-row
    //          matrix rows[CB][NBC] (96 KB) ALIASES the arena head —
    //          consumed by scan before fill writes the arena.
    size_t oCur   = 4096;
    size_t oBase  = oCur + (size_t)NBC * CURP * 4;           // 20480
    size_t oFint0 = align256(oBase + 4 * (NBC + 1));         // 21760
    size_t rowsBytes = (size_t)CB * NBC * 4;                 // 98304

    const int cfgK[6] = {1, 2, 2, 4, 4, 8};
    const int cfgM[6] = {0, 1, 2, 1, 2, 2};
    int K = 8, mode = 2;
    size_t oF = oFint0, oA = oFint0;
    for (int t = 0; t < 6; ++t) {
        int Kc = cfgK[t], Mc = cfgM[t];
        size_t chunkE = (size_t)(E + Kc - 1) / Kc;
        size_t fsz = (Kc > 1) ? (size_t)3 * N * (Mc == 1 ? 4 : 2) : 0;
        size_t oAt = align256(oFint0 + fsz);
        size_t arenaB = 2 * chunkE * 8;
        if (arenaB < rowsBytes) arenaB = rowsBytes;   // alias safety for tiny E
        size_t need = oAt + arenaB;
        if (need <= ws_size || t == 5) {
            K = Kc; mode = Mc; oF = oFint0; oA = oAt;
            if (need <= ws_size) break;
        }
    }

    int chunkElems = (E + K - 1) / K;

    double*             accSlots = (double*)d_ws;
    int*                cursor   = (int*)((char*)d_ws + oCur);
    int*                base     = (int*)((char*)d_ws + oBase);
    float*              fint32   = (float*)((char*)d_ws + oF);
    __half*             fint16   = (__half*)((char*)d_ws + oF);
    uint2*              arena    = (uint2*)((char*)d_ws + oA);
    unsigned long long* arenaLL  = (unsigned long long*)arena;
    int*                rows     = (int*)arena;       // alias, pre-fill only

    for (int c = 0; c < K; ++c) {
        int cs = c * chunkElems;
        if (cs >= E) break;
        int ce = cs + chunkElems;
        if (ce > E) ce = E;
        int NT = (ce - cs + FBE - 1) / FBE;

        int isFirst = (c == 0);
        int isLast  = (ce == E);

        count_kernel<<<CB, 1024, 0, stream>>>(conn, rows, cs, ce);
        scan_kernel<<<1, 1024, 0, stream>>>(rows, cursor, base, accSlots, isFirst);
        fill_kernel<<<NT, FTH, 0, stream>>>(
            conn, pred, u_c, theta_c, len, pE, pA, pI, dir,
            arena, cursor, cs, ce);
        accum_kernel<<<NBc, ATH, 0, stream>>>(
            arenaLL, base, Fext, bcd, bcr, accSlots,
            fint32, fint16, N, isFirst, isLast, mode);
    }

    final_kernel<<<1, 64, 0, stream>>>(accSlots, (float*)d_out);
}

// Round 7
// 276.331 us; speedup vs baseline: 1.0972x; 1.0086x over previous
//
#include <hip/hip_runtime.h>
#include <hip/hip_fp16.h>

// Arena-contiguous scatter/gather, v6 (fp16-packed gather target):
//   upack : once per call; u_phys = pred*scale packed to fp16x3 in ONE
//           aligned 8B word/node (8 MB). fill's random gather working set
//           drops 12->8 MB (better per-XCD L2 hit) and loses all line
//           straddles (12B unaligned -> 8B aligned dwordx2).
//   count : 96 blocks; per-block LDS histogram (256 coarse buckets) ->
//           plain nt-store rows (aliased into arena head).
//   scan  : 1 block; column-reduce rows, block scan -> base[NBC+1]; init
//           padded cursors; zero accSlots on first chunk.
//   fill  : tile = 2048 elems; ONE-stage LDS bucket sort; coalesced nt flush
//           into the bucket's contiguous arena range.
//   accum : block = coarse bucket (48KB fp32 tile); dense nt arena stream;
//           fp16 nt partial F_int across chunks; fused masked loss on last.
//   final : 1 wave reduces 64 slot pairs, divides, writes out[0].
// Records: 8B {fx16,fy16 | local12,fz16}. Ladder (all with upack):
//   K=1 no-partial 40.1MB / K=2 30.0MB / K=3 24.7MB (guaranteed) / ...
// All streaming stores nontemporal so upack stays L2-resident.

#define SPANC  4096          // nodes per coarse bucket
#define NBC    256           // max coarse buckets
#define CURP   16            // ints per padded cursor slot (64 B line)
#define FTH    1024          // fill threads
#define FBE    2048          // elems per fill tile (4096 records = one slab)
#define ATH    1024          // accum threads
#define CB     96            // count blocks (plain-store rows)

struct F3 { float x, y, z; };

__device__ __forceinline__ uint2 packrec(float fx, float fy, float fz, int local) {
    unsigned short hx = __half_as_ushort(__float2half(fx));
    unsigned short hy = __half_as_ushort(__float2half(fy));
    unsigned short hz = __half_as_ushort(__float2half(fz));
    return make_uint2(((unsigned)hy << 16) | hx, ((unsigned)local << 16) | hz);
}

// 1024-thread inclusive scan. Call sites must be separated by __syncthreads().
__device__ __forceinline__ int block_incl_scan(int v, int* wsum, int lane, int wv) {
    #pragma unroll
    for (int off = 1; off < 64; off <<= 1) {
        int t = __shfl_up(v, off, 64);
        if (lane >= off) v += t;
    }
    if (lane == 63) wsum[wv] = v;
    __syncthreads();
    if (wv == 0) {
        int w = (lane < 16) ? wsum[lane] : 0;
        #pragma unroll
        for (int off = 1; off < 16; off <<= 1) {
            int t = __shfl_up(w, off, 64);
            if (lane >= off) w += t;
        }
        if (lane < 16) wsum[lane] = w;
    }
    __syncthreads();
    return v + ((wv > 0) ? wsum[wv - 1] : 0);
}

__global__ void __launch_bounds__(1024)
upack_kernel(const float* __restrict__ pred, const float* __restrict__ u_c,
             const float* __restrict__ theta_c, uint2* __restrict__ up, int N) {
    int i = blockIdx.x * 1024 + threadIdx.x;
    if (i >= N) return;
    float uc = u_c[0], tc = theta_c[0];
    float x = __builtin_nontemporal_load(&pred[3 * i + 0]) * uc;
    float y = __builtin_nontemporal_load(&pred[3 * i + 1]) * uc;
    float z = __builtin_nontemporal_load(&pred[3 * i + 2]) * tc;
    unsigned hx = __half_as_ushort(__float2half(x));
    unsigned hy = __half_as_ushort(__float2half(y));
    unsigned hz = __half_as_ushort(__float2half(z));
    up[i] = make_uint2((hy << 16) | hx, hz);   // temporal: want L2-resident
}

__global__ void __launch_bounds__(1024)
count_kernel(const long long* __restrict__ conn, int* __restrict__ rows,
             int cs, int ce) {
    __shared__ int h[NBC];
    int tid = threadIdx.x;
    if (tid < NBC) h[tid] = 0;
    __syncthreads();
    int stride = gridDim.x * 1024;
    for (int e = cs + blockIdx.x * 1024 + tid; e < ce; e += stride) {
        long long v = __builtin_nontemporal_load(conn + e);
        int na = (int)(unsigned)((unsigned long long)v & 0xFFFFFFFFull);
        int nb = (int)(unsigned)((unsigned long long)v >> 32);
        atomicAdd(&h[na >> 12], 1);
        atomicAdd(&h[nb >> 12], 1);
    }
    __syncthreads();
    if (tid < NBC)
        __builtin_nontemporal_store(h[tid], &rows[blockIdx.x * NBC + tid]);
}

__global__ void __launch_bounds__(1024)
scan_kernel(const int* __restrict__ rows, int* __restrict__ cursor,
            int* __restrict__ base, double* __restrict__ accSlots,
            int isFirst) {
    __shared__ int wsum[16];
    int tid = threadIdx.x, lane = tid & 63, wv = tid >> 6;
    int c = 0;
    if (tid < NBC) {
        #pragma unroll 4
        for (int r = 0; r < CB; ++r) c += rows[r * NBC + tid];
    }
    int incl = block_incl_scan(c, wsum, lane, wv);
    if (tid < NBC) {
        base[tid + 1] = incl;
        cursor[tid * CURP] = incl - c;   // cursor = exclusive start
    }
    if (tid == 0) base[0] = 0;
    if (isFirst && tid < 512) accSlots[tid] = 0.0;
}

__global__ void __launch_bounds__(1024)
fill_kernel(const long long* __restrict__ conn,
            const uint2* __restrict__ upk,
            const float* __restrict__ len,
            const float* __restrict__ pE,
            const float* __restrict__ pA,
            const float* __restrict__ pI,
            const float* __restrict__ dir,
            uint2* __restrict__ arena,
            int* __restrict__ cursor,
            int cs, int ce) {
    __shared__ uint2         slab[2 * FBE];   // 4096 recs, 32KB
    __shared__ unsigned char sbk [2 * FBE];   // 4KB (bucket < 256)
    __shared__ int hist [NBC];                // 1KB
    __shared__ int boff [NBC];                // 1KB  block-local bucket start
    __shared__ int astart[NBC];               // 1KB  arena start per bucket
    __shared__ int wsum [16];
    // total ~39.3KB -> 2 blocks/CU (thread-capped), 32 waves/CU

    int tid = threadIdx.x, lane = tid & 63, wv = tid >> 6;

    if (tid < NBC) hist[tid] = 0;
    __syncthreads();

    int bs = cs + blockIdx.x * FBE;
    int be = bs + FBE; if (be > ce) be = ce;

    unsigned sv[4];   // (rank<<8)|bucket ; 0xFFFFFFFF = none
    uint2    rc[4];

    #pragma unroll
    for (int j = 0; j < 2; ++j) {
        int e = bs + j * FTH + tid;
        unsigned sa = 0xFFFFFFFFu, sb = 0xFFFFFFFFu;
        if (e < be) {
            long long cv = __builtin_nontemporal_load(conn + e);
            int na = (int)(unsigned)((unsigned long long)cv & 0xFFFFFFFFull);
            int nb = (int)(unsigned)((unsigned long long)cv >> 32);

            uint2 ua = upk[na];           // temporal 8B aligned gather
            uint2 ub = upk[nb];

            float c  = __builtin_nontemporal_load(&dir[3 * e + 0]);
            float s  = __builtin_nontemporal_load(&dir[3 * e + 2]);
            float L  = __builtin_nontemporal_load(&len[e]);
            float Ee = __builtin_nontemporal_load(&pE[e]);
            float EA = Ee * __builtin_nontemporal_load(&pA[e]);
            float EI = Ee * __builtin_nontemporal_load(&pI[e]);

            float a0 = __half2float(__ushort_as_half((unsigned short)(ua.x & 0xFFFFu)));
            float a1 = __half2float(__ushort_as_half((unsigned short)(ua.x >> 16)));
            float a2 = __half2float(__ushort_as_half((unsigned short)(ua.y & 0xFFFFu)));
            float b0 = __half2float(__ushort_as_half((unsigned short)(ub.x & 0xFFFFu)));
            float b1 = __half2float(__ushort_as_half((unsigned short)(ub.x >> 16)));
            float b2 = __half2float(__ushort_as_half((unsigned short)(ub.y & 0xFFFFu)));

            float u_A  =  c * a0 + s * a1;
            float w_A  = -s * a0 + c * a1;
            float th_A = -a2;
            float u_B  =  c * b0 + s * b1;
            float w_B  = -s * b0 + c * b1;
            float th_B = -b2;

            float invL  = 1.0f / L;
            float ea_l  = EA * invL;             // AXIAL_WEIGHT = 1.0
            float ei_l  = EI * invL;
            float ei_l2 = ei_l  * invL;
            float ei_l3 = ei_l2 * invL;

            float dw = w_A - w_B;
            float f0 = ea_l * (u_A - u_B);
            float f1 = 12.0f * ei_l3 * dw + 6.0f * ei_l2 * (th_A + th_B);
            float f2 = 6.0f * ei_l2 * dw + 4.0f * ei_l * th_A + 2.0f * ei_l * th_B;
            float f5 = 6.0f * ei_l2 * dw + 2.0f * ei_l * th_A + 4.0f * ei_l * th_B;

            float fA0 = c * f0 - s * f1;
            float fA1 = s * f0 + c * f1;

            int bkA = na >> 12;
            int rA  = atomicAdd(&hist[bkA], 1);
            sa = ((unsigned)rA << 8) | (unsigned)bkA;
            rc[2 * j + 0] = packrec(fA0, fA1, -f2, na & 4095);

            int bkB = nb >> 12;
            int rB  = atomicAdd(&hist[bkB], 1);
            sb = ((unsigned)rB << 8) | (unsigned)bkB;
            rc[2 * j + 1] = packrec(-fA0, -fA1, -f5, nb & 4095);
        }
        sv[2 * j + 0] = sa;
        sv[2 * j + 1] = sb;
    }
    __syncthreads();

    // one arena reservation per (tile,bucket); single scan gives local layout
    int h = (tid < NBC) ? hist[tid] : 0;
    if (tid < NBC && h) astart[tid] = atomicAdd(&cursor[tid * CURP], h);
    int iT = block_incl_scan(h, wsum, lane, wv);   // internal syncs order astart
    if (tid < NBC) boff[tid] = iT - h;
    __syncthreads();

    // scatter into slab, sorted by bucket
    #pragma unroll
    for (int r = 0; r < 4; ++r) {
        unsigned s2 = sv[r];
        if (s2 != 0xFFFFFFFFu) {
            int bk = (int)(s2 & 255u);
            int rk = (int)(s2 >> 8);
            int slot = boff[bk] + rk;
            slab[slot] = rc[r];
            sbk[slot]  = (unsigned char)bk;
        }
    }
    __syncthreads();

    // coalesced nt flush: ~16-record runs contiguous in slab and arena
    int tot = boff[NBC - 1] + hist[NBC - 1];
    for (int i = tid; i < tot; i += FTH) {
        int bk = sbk[i];
        uint2 r2 = slab[i];
        unsigned long long v = ((unsigned long long)r2.y << 32) | (unsigned long long)r2.x;
        __builtin_nontemporal_store(v,
            (unsigned long long*)&arena[astart[bk] + (i - boff[bk])]);
    }
}

__global__ void __launch_bounds__(1024)
accum_kernel(const unsigned long long* __restrict__ arena,
             const int* __restrict__ base,
             const float* __restrict__ Fext,
             const float* __restrict__ bcd,
             const float* __restrict__ bcr,
             double* __restrict__ accSlots,
             float* __restrict__ fint32,
             unsigned short* __restrict__ fint16,
             int N, int isFirst, int isLast, int mode) {
    __shared__ float tile[SPANC * 3];   // 48KB
    __shared__ double sn[16], sd[16];

    int tid = threadIdx.x, lane = tid & 63, wv = tid >> 6;
    int b = blockIdx.x;
    int nodeLo = b * SPANC;
    int gBase = nodeLo * 3;
    int gMax  = 3 * N;

    if (isFirst) {
        for (int i = tid; i < SPANC * 3; i += ATH) tile[i] = 0.0f;
    } else if (mode == 1) {
        for (int i = tid; i < SPANC * 3; i += ATH) {
            int g = gBase + i;
            tile[i] = (g < gMax) ? __builtin_nontemporal_load(&fint32[g]) : 0.0f;
        }
    } else {
        for (int i = tid; i < SPANC * 3; i += ATH) {
            int g = gBase + i;
            tile[i] = (g < gMax)
                ? __half2float(__ushort_as_half(__builtin_nontemporal_load(&fint16[g])))
                : 0.0f;
        }
    }
    __syncthreads();

    // dense coalesced replay of this bucket's contiguous arena range
    int s0 = base[b];
    int s1 = base[b + 1];
    for (int i = s0 + tid; i < s1; i += ATH) {
        unsigned long long rv = __builtin_nontemporal_load(arena + i);
        unsigned lo = (unsigned)(rv & 0xFFFFFFFFull);
        unsigned hi = (unsigned)(rv >> 32);
        float fx = __half2float(__ushort_as_half((unsigned short)(lo & 0xFFFFu)));
        float fy = __half2float(__ushort_as_half((unsigned short)(lo >> 16)));
        float fz = __half2float(__ushort_as_half((unsigned short)(hi & 0xFFFFu)));
        int local = (int)(hi >> 16);
        atomicAdd(&tile[local * 3 + 0], fx);
        atomicAdd(&tile[local * 3 + 1], fy);
        atomicAdd(&tile[local * 3 + 2], fz);
    }
    __syncthreads();

    if (!isLast) {
        if (mode == 1) {
            for (int i = tid; i < SPANC * 3; i += ATH) {
                int g = gBase + i;
                if (g < gMax) __builtin_nontemporal_store(tile[i], &fint32[g]);
            }
        } else {
            for (int i = tid; i < SPANC * 3; i += ATH) {
                int g = gBase + i;
                if (g < gMax)
                    __builtin_nontemporal_store(
                        __half_as_ushort(__float2half(tile[i])), &fint16[g]);
            }
        }
        return;
    }

    // fused masked loss over this bucket's node range
    int spanCnt = N - nodeLo;
    if (spanCnt > SPANC) spanCnt = SPANC;

    double num = 0.0, den = 0.0;
    for (int l = tid; l < spanCnt; l += ATH) {
        int n = nodeLo + l;
        float md = 1.0f - __builtin_nontemporal_load(&bcd[n]);
        float mr = 1.0f - __builtin_nontemporal_load(&bcr[n]);
        float e0 = __builtin_nontemporal_load(&Fext[3 * n + 0]);
        float e1 = __builtin_nontemporal_load(&Fext[3 * n + 1]);
        float e2 = __builtin_nontemporal_load(&Fext[3 * n + 2]);
        float r0 = (tile[l * 3 + 0] - e0) * md;
        float r1 = (tile[l * 3 + 1] - e1) * md;
        float r2 = (tile[l * 3 + 2] - e2) * mr;
        float g0 = e0 * md;
        float g1 = e1 * md;
        float g2 = e2 * mr;
        num += (double)r0 * r0 + (double)r1 * r1 + (double)r2 * r2;
        den += (double)g0 * g0 + (double)g1 * g1 + (double)g2 * g2;
    }
    #pragma unroll
    for (int off = 32; off > 0; off >>= 1) {
        num += __shfl_down(num, off, 64);
        den += __shfl_down(den, off, 64);
    }
    if (lane == 0) { sn[wv] = num; sd[wv] = den; }
    __syncthreads();
    if (tid == 0) {
        double tn = 0.0, td = 0.0;
        #pragma unroll
        for (int w = 0; w < 16; ++w) { tn += sn[w]; td += sd[w]; }
        double* slot = accSlots + (size_t)(b & 63) * 8;
        atomicAdd(&slot[0], tn);
        atomicAdd(&slot[1], td);
    }
}

__global__ void final_kernel(const double* __restrict__ accSlots,
                             float* __restrict__ out) {
    int t = threadIdx.x;   // 64 threads
    double n = accSlots[t * 8 + 0];
    double d = accSlots[t * 8 + 1];
    #pragma unroll
    for (int off = 32; off > 0; off >>= 1) {
        n += __shfl_down(n, off, 64);
        d += __shfl_down(d, off, 64);
    }
    if (t == 0) {
        if (d < 1e-30) d = 1e-30;
        out[0] = (float)(n / d);
    }
}

static inline size_t align256(size_t x) { return (x + 255) & ~(size_t)255; }

extern "C" void kernel_launch(void* const* d_in, const int* in_sizes, int n_in,
                              void* d_out, int out_size, void* d_ws, size_t ws_size,
                              hipStream_t stream) {
    const float* pred    = (const float*)d_in[0];
    const float* u_c     = (const float*)d_in[1];
    const float* theta_c = (const float*)d_in[2];
    const float* len     = (const float*)d_in[3];
    const float* pE      = (const float*)d_in[4];
    const float* pA      = (const float*)d_in[5];
    const float* pI      = (const float*)d_in[6];
    const float* dir     = (const float*)d_in[7];
    const float* Fext    = (const float*)d_in[8];
    const float* bcd     = (const float*)d_in[9];
    const float* bcr     = (const float*)d_in[10];
    const long long* conn = (const long long*)d_in[11];

    int N = in_sizes[0] / 3;
    int E = in_sizes[3];
    int NBc = (N + SPANC - 1) / SPANC;   // coarse buckets, must be <= NBC

    // Workspace layout:
    //   0      accSlots   4096 B (64 slots * 64B)
    //   4096   cursors    NBC*CURP*4 = 16384 B
    //   20480  base       (NBC+1)*4 B
    //   21760  upack      8*N B (fp16x3+pad per node, ALWAYS present)
    //   oFint  fp16/fp32 partial F_int (K>1 only)
    //   oArena arena: 2*chunkElems records * 8 B; count-row matrix
    //          rows[CB][NBC] (96 KB) aliases the arena head (consumed by
    //          scan before fill writes).
    size_t oCur   = 4096;
    size_t oBase  = oCur + (size_t)NBC * CURP * 4;           // 20480
    size_t oU     = align256(oBase + 4 * (NBC + 1));         // 21760
    size_t upB    = (size_t)N * 8;
    size_t oFint0 = align256(oU + upB);
    size_t rowsBytes = (size_t)CB * NBC * 4;                 // 98304

    // Ladder (all rungs use upack): K chunks, partial mode (0 none/1 fp32/2 fp16)
    const int cfgK[6] = {1, 2, 3, 4, 6, 8};
    const int cfgM[6] = {0, 2, 2, 2, 2, 2};
    int K = 8, mode = 2;
    size_t oF = oFint0, oA = oFint0;
    for (int t = 0; t < 6; ++t) {
        int Kc = cfgK[t], Mc = cfgM[t];
        size_t chunkE = (size_t)(E + Kc - 1) / Kc;
        size_t fsz = (Kc > 1) ? (size_t)3 * N * (Mc == 1 ? 4 : 2) : 0;
        size_t oAt = align256(oFint0 + fsz);
        size_t arenaB = 2 * chunkE * 8;
        if (arenaB < rowsBytes) arenaB = rowsBytes;   // alias safety for tiny E
        size_t need = oAt + arenaB;
        if (need <= ws_size || t == 5) {
            K = Kc; mode = Mc; oF = oFint0; oA = oAt;
            if (need <= ws_size) break;
        }
    }

    int chunkElems = (E + K - 1) / K;

    double*             accSlots = (double*)d_ws;
    int*                cursor   = (int*)((char*)d_ws + oCur);
    int*                base     = (int*)((char*)d_ws + oBase);
    uint2*              upk      = (uint2*)((char*)d_ws + oU);
    float*              fint32   = (float*)((char*)d_ws + oF);
    unsigned short*     fint16   = (unsigned short*)((char*)d_ws + oF);
    uint2*              arena    = (uint2*)((char*)d_ws + oA);
    unsigned long long* arenaLL  = (unsigned long long*)arena;
    int*                rows     = (int*)arena;       // alias, pre-fill only

    upack_kernel<<<(N + 1023) / 1024, 1024, 0, stream>>>(pred, u_c, theta_c, upk, N);

    for (int c = 0; c < K; ++c) {
        int cs = c * chunkElems;
        if (cs >= E) break;
        int ce = cs + chunkElems;
        if (ce > E) ce = E;
        int NT = (ce - cs + FBE - 1) / FBE;

        int isFirst = (c == 0);
        int isLast  = (ce == E);

        count_kernel<<<CB, 1024, 0, stream>>>(conn, rows, cs, ce);
        scan_kernel<<<1, 1024, 0, stream>>>(rows, cursor, base, accSlots, isFirst);
        fill_kernel<<<NT, FTH, 0, stream>>>(
            conn, upk, len, pE, pA, pI, dir, arena, cursor, cs, ce);
        accum_kernel<<<NBc, ATH, 0, stream>>>(
            arenaLL, base, Fext, bcd, bcr, accSlots,
            fint32, fint16, N, isFirst, isLast, mode);
    }

    final_kernel<<<1, 64, 0, stream>>>(accSlots, (float*)d_out);
}

// Round 8
// 223.530 us; speedup vs baseline: 1.3564x; 1.2362x over previous
//
#include <hip/hip_runtime.h>
#include <hip/hip_fp16.h>

// Arena-contiguous scatter/gather, v7 (integer LDS accumulation):
//   v6 post-mortem: accum's fp32 LDS atomicAdd lowers to a CAS retry loop on
//   gfx950 (no -munsafe-fp-atomics) -> ~73us fixed cost, memory-independent
//   (rocprof: warm replay with 15KB HBM traffic still 72.7us). Fix: fixed-
//   point int tile (scale 2^13) + native ds_add_u32 atomics. Int sums are
//   exact; 1.2e-4 quantization is far below the fp16 record precision.
//   upack : u_phys = pred*scale packed to fp16x3 in one aligned 8B word/node
//           (8 MB gather target, L2-friendly, no line straddles).
//   count : 96 blocks; per-block LDS histogram (256 coarse buckets) -> rows.
//   scan  : 1 block; column-reduce rows, scan -> base[NBC+1]; init cursors.
//   fill  : tile = 2048 elems; ONE-stage LDS bucket sort; coalesced nt flush
//           into the bucket's contiguous arena range.
//   accum : block = coarse bucket (48KB int tile); dense nt arena stream;
//           int fixed-point adds; fp16 partial across chunks; fused loss.
//   final : 1 wave reduces 64 slot pairs, divides, writes out[0].
// Records: 8B {fx16,fy16 | local12,fz16}. Ladder: K=2 fp16-partial = 30.0MB.

#define SPANC  4096          // nodes per coarse bucket
#define NBC    256           // max coarse buckets
#define CURP   16            // ints per padded cursor slot (64 B line)
#define FTH    1024          // fill threads
#define FBE    2048          // elems per fill tile (4096 records = one slab)
#define ATH    1024          // accum threads
#define CB     96            // count blocks (plain-store rows)
#define QSCALE 8192.0f       // 2^13 fixed-point scale
#define QINV   1.220703125e-4f

struct F3 { float x, y, z; };

__device__ __forceinline__ uint2 packrec(float fx, float fy, float fz, int local) {
    unsigned short hx = __half_as_ushort(__float2half(fx));
    unsigned short hy = __half_as_ushort(__float2half(fy));
    unsigned short hz = __half_as_ushort(__float2half(fz));
    return make_uint2(((unsigned)hy << 16) | hx, ((unsigned)local << 16) | hz);
}

// 1024-thread inclusive scan. Call sites must be separated by __syncthreads().
__device__ __forceinline__ int block_incl_scan(int v, int* wsum, int lane, int wv) {
    #pragma unroll
    for (int off = 1; off < 64; off <<= 1) {
        int t = __shfl_up(v, off, 64);
        if (lane >= off) v += t;
    }
    if (lane == 63) wsum[wv] = v;
    __syncthreads();
    if (wv == 0) {
        int w = (lane < 16) ? wsum[lane] : 0;
        #pragma unroll
        for (int off = 1; off < 16; off <<= 1) {
            int t = __shfl_up(w, off, 64);
            if (lane >= off) w += t;
        }
        if (lane < 16) wsum[lane] = w;
    }
    __syncthreads();
    return v + ((wv > 0) ? wsum[wv - 1] : 0);
}

__global__ void __launch_bounds__(1024)
upack_kernel(const float* __restrict__ pred, const float* __restrict__ u_c,
             const float* __restrict__ theta_c, uint2* __restrict__ up, int N) {
    int i = blockIdx.x * 1024 + threadIdx.x;
    if (i >= N) return;
    float uc = u_c[0], tc = theta_c[0];
    float x = __builtin_nontemporal_load(&pred[3 * i + 0]) * uc;
    float y = __builtin_nontemporal_load(&pred[3 * i + 1]) * uc;
    float z = __builtin_nontemporal_load(&pred[3 * i + 2]) * tc;
    unsigned hx = __half_as_ushort(__float2half(x));
    unsigned hy = __half_as_ushort(__float2half(y));
    unsigned hz = __half_as_ushort(__float2half(z));
    up[i] = make_uint2((hy << 16) | hx, hz);   // temporal: want L2-resident
}

__global__ void __launch_bounds__(1024)
count_kernel(const long long* __restrict__ conn, int* __restrict__ rows,
             int cs, int ce) {
    __shared__ int h[NBC];
    int tid = threadIdx.x;
    if (tid < NBC) h[tid] = 0;
    __syncthreads();
    int stride = gridDim.x * 1024;
    for (int e = cs + blockIdx.x * 1024 + tid; e < ce; e += stride) {
        long long v = __builtin_nontemporal_load(conn + e);
        int na = (int)(unsigned)((unsigned long long)v & 0xFFFFFFFFull);
        int nb = (int)(unsigned)((unsigned long long)v >> 32);
        atomicAdd(&h[na >> 12], 1);
        atomicAdd(&h[nb >> 12], 1);
    }
    __syncthreads();
    if (tid < NBC)
        __builtin_nontemporal_store(h[tid], &rows[blockIdx.x * NBC + tid]);
}

__global__ void __launch_bounds__(1024)
scan_kernel(const int* __restrict__ rows, int* __restrict__ cursor,
            int* __restrict__ base, double* __restrict__ accSlots,
            int isFirst) {
    __shared__ int wsum[16];
    int tid = threadIdx.x, lane = tid & 63, wv = tid >> 6;
    int c = 0;
    if (tid < NBC) {
        #pragma unroll 4
        for (int r = 0; r < CB; ++r) c += rows[r * NBC + tid];
    }
    int incl = block_incl_scan(c, wsum, lane, wv);
    if (tid < NBC) {
        base[tid + 1] = incl;
        cursor[tid * CURP] = incl - c;   // cursor = exclusive start
    }
    if (tid == 0) base[0] = 0;
    if (isFirst && tid < 512) accSlots[tid] = 0.0;
}

__global__ void __launch_bounds__(1024)
fill_kernel(const long long* __restrict__ conn,
            const uint2* __restrict__ upk,
            const float* __restrict__ len,
            const float* __restrict__ pE,
            const float* __restrict__ pA,
            const float* __restrict__ pI,
            const float* __restrict__ dir,
            uint2* __restrict__ arena,
            int* __restrict__ cursor,
            int cs, int ce) {
    __shared__ uint2         slab[2 * FBE];   // 4096 recs, 32KB
    __shared__ unsigned char sbk [2 * FBE];   // 4KB (bucket < 256)
    __shared__ int hist [NBC];                // 1KB
    __shared__ int boff [NBC];                // 1KB  block-local bucket start
    __shared__ int astart[NBC];               // 1KB  arena start per bucket
    __shared__ int wsum [16];
    // total ~39.3KB -> 2 blocks/CU (thread-capped), 32 waves/CU

    int tid = threadIdx.x, lane = tid & 63, wv = tid >> 6;

    if (tid < NBC) hist[tid] = 0;
    __syncthreads();

    int bs = cs + blockIdx.x * FBE;
    int be = bs + FBE; if (be > ce) be = ce;

    unsigned sv[4];   // (rank<<8)|bucket ; 0xFFFFFFFF = none
    uint2    rc[4];

    #pragma unroll
    for (int j = 0; j < 2; ++j) {
        int e = bs + j * FTH + tid;
        unsigned sa = 0xFFFFFFFFu, sb = 0xFFFFFFFFu;
        if (e < be) {
            long long cv = __builtin_nontemporal_load(conn + e);
            int na = (int)(unsigned)((unsigned long long)cv & 0xFFFFFFFFull);
            int nb = (int)(unsigned)((unsigned long long)cv >> 32);

            uint2 ua = upk[na];           // temporal 8B aligned gather
            uint2 ub = upk[nb];

            float c  = __builtin_nontemporal_load(&dir[3 * e + 0]);
            float s  = __builtin_nontemporal_load(&dir[3 * e + 2]);
            float L  = __builtin_nontemporal_load(&len[e]);
            float Ee = __builtin_nontemporal_load(&pE[e]);
            float EA = Ee * __builtin_nontemporal_load(&pA[e]);
            float EI = Ee * __builtin_nontemporal_load(&pI[e]);

            float a0 = __half2float(__ushort_as_half((unsigned short)(ua.x & 0xFFFFu)));
            float a1 = __half2float(__ushort_as_half((unsigned short)(ua.x >> 16)));
            float a2 = __half2float(__ushort_as_half((unsigned short)(ua.y & 0xFFFFu)));
            float b0 = __half2float(__ushort_as_half((unsigned short)(ub.x & 0xFFFFu)));
            float b1 = __half2float(__ushort_as_half((unsigned short)(ub.x >> 16)));
            float b2 = __half2float(__ushort_as_half((unsigned short)(ub.y & 0xFFFFu)));

            float u_A  =  c * a0 + s * a1;
            float w_A  = -s * a0 + c * a1;
            float th_A = -a2;
            float u_B  =  c * b0 + s * b1;
            float w_B  = -s * b0 + c * b1;
            float th_B = -b2;

            float invL  = 1.0f / L;
            float ea_l  = EA * invL;             // AXIAL_WEIGHT = 1.0
            float ei_l  = EI * invL;
            float ei_l2 = ei_l  * invL;
            float ei_l3 = ei_l2 * invL;

            float dw = w_A - w_B;
            float f0 = ea_l * (u_A - u_B);
            float f1 = 12.0f * ei_l3 * dw + 6.0f * ei_l2 * (th_A + th_B);
            float f2 = 6.0f * ei_l2 * dw + 4.0f * ei_l * th_A + 2.0f * ei_l * th_B;
            float f5 = 6.0f * ei_l2 * dw + 2.0f * ei_l * th_A + 4.0f * ei_l * th_B;

            float fA0 = c * f0 - s * f1;
            float fA1 = s * f0 + c * f1;

            int bkA = na >> 12;
            int rA  = atomicAdd(&hist[bkA], 1);
            sa = ((unsigned)rA << 8) | (unsigned)bkA;
            rc[2 * j + 0] = packrec(fA0, fA1, -f2, na & 4095);

            int bkB = nb >> 12;
            int rB  = atomicAdd(&hist[bkB], 1);
            sb = ((unsigned)rB << 8) | (unsigned)bkB;
            rc[2 * j + 1] = packrec(-fA0, -fA1, -f5, nb & 4095);
        }
        sv[2 * j + 0] = sa;
        sv[2 * j + 1] = sb;
    }
    __syncthreads();

    // one arena reservation per (tile,bucket); single scan gives local layout
    int h = (tid < NBC) ? hist[tid] : 0;
    if (tid < NBC && h) astart[tid] = atomicAdd(&cursor[tid * CURP], h);
    int iT = block_incl_scan(h, wsum, lane, wv);   // internal syncs order astart
    if (tid < NBC) boff[tid] = iT - h;
    __syncthreads();

    // scatter into slab, sorted by bucket
    #pragma unroll
    for (int r = 0; r < 4; ++r) {
        unsigned s2 = sv[r];
        if (s2 != 0xFFFFFFFFu) {
            int bk = (int)(s2 & 255u);
            int rk = (int)(s2 >> 8);
            int slot = boff[bk] + rk;
            slab[slot] = rc[r];
            sbk[slot]  = (unsigned char)bk;
        }
    }
    __syncthreads();

    // coalesced nt flush: ~16-record runs contiguous in slab and arena
    int tot = boff[NBC - 1] + hist[NBC - 1];
    for (int i = tid; i < tot; i += FTH) {
        int bk = sbk[i];
        uint2 r2 = slab[i];
        unsigned long long v = ((unsigned long long)r2.y << 32) | (unsigned long long)r2.x;
        __builtin_nontemporal_store(v,
            (unsigned long long*)&arena[astart[bk] + (i - boff[bk])]);
    }
}

__global__ void __launch_bounds__(1024)
accum_kernel(const unsigned long long* __restrict__ arena,
             const int* __restrict__ base,
             const float* __restrict__ Fext,
             const float* __restrict__ bcd,
             const float* __restrict__ bcr,
             double* __restrict__ accSlots,
             int* __restrict__ fintI,
             unsigned short* __restrict__ fint16,
             int N, int isFirst, int isLast, int mode) {
    __shared__ int tile[SPANC * 3];   // 48KB fixed-point (2^13)
    __shared__ double sn[16], sd[16];

    int tid = threadIdx.x, lane = tid & 63, wv = tid >> 6;
    int b = blockIdx.x;
    int nodeLo = b * SPANC;
    int gBase = nodeLo * 3;
    int gMax  = 3 * N;

    if (isFirst) {
        for (int i = tid; i < SPANC * 3; i += ATH) tile[i] = 0;
    } else if (mode == 1) {
        for (int i = tid; i < SPANC * 3; i += ATH) {
            int g = gBase + i;
            tile[i] = (g < gMax) ? __builtin_nontemporal_load(&fintI[g]) : 0;
        }
    } else {
        for (int i = tid; i < SPANC * 3; i += ATH) {
            int g = gBase + i;
            tile[i] = (g < gMax)
                ? __float2int_rn(__half2float(__ushort_as_half(
                      __builtin_nontemporal_load(&fint16[g]))) * QSCALE)
                : 0;
        }
    }
    __syncthreads();

    // dense coalesced replay; NATIVE int LDS atomics (ds_add), no CAS loop
    int s0 = base[b];
    int s1 = base[b + 1];
    for (int i = s0 + tid; i < s1; i += ATH) {
        unsigned long long rv = __builtin_nontemporal_load(arena + i);
        unsigned lo = (unsigned)(rv & 0xFFFFFFFFull);
        unsigned hi = (unsigned)(rv >> 32);
        float fx = __half2float(__ushort_as_half((unsigned short)(lo & 0xFFFFu)));
        float fy = __half2float(__ushort_as_half((unsigned short)(lo >> 16)));
        float fz = __half2float(__ushort_as_half((unsigned short)(hi & 0xFFFFu)));
        int local = (int)(hi >> 16);
        atomicAdd(&tile[local * 3 + 0], __float2int_rn(fx * QSCALE));
        atomicAdd(&tile[local * 3 + 1], __float2int_rn(fy * QSCALE));
        atomicAdd(&tile[local * 3 + 2], __float2int_rn(fz * QSCALE));
    }
    __syncthreads();

    if (!isLast) {
        if (mode == 1) {
            for (int i = tid; i < SPANC * 3; i += ATH) {
                int g = gBase + i;
                if (g < gMax) __builtin_nontemporal_store(tile[i], &fintI[g]);
            }
        } else {
            for (int i = tid; i < SPANC * 3; i += ATH) {
                int g = gBase + i;
                if (g < gMax)
                    __builtin_nontemporal_store(
                        __half_as_ushort(__float2half((float)tile[i] * QINV)),
                        &fint16[g]);
            }
        }
        return;
    }

    // fused masked loss over this bucket's node range
    int spanCnt = N - nodeLo;
    if (spanCnt > SPANC) spanCnt = SPANC;

    double num = 0.0, den = 0.0;
    for (int l = tid; l < spanCnt; l += ATH) {
        int n = nodeLo + l;
        float md = 1.0f - __builtin_nontemporal_load(&bcd[n]);
        float mr = 1.0f - __builtin_nontemporal_load(&bcr[n]);
        float e0 = __builtin_nontemporal_load(&Fext[3 * n + 0]);
        float e1 = __builtin_nontemporal_load(&Fext[3 * n + 1]);
        float e2 = __builtin_nontemporal_load(&Fext[3 * n + 2]);
        float t0 = (float)tile[l * 3 + 0] * QINV;
        float t1 = (float)tile[l * 3 + 1] * QINV;
        float t2 = (float)tile[l * 3 + 2] * QINV;
        float r0 = (t0 - e0) * md;
        float r1 = (t1 - e1) * md;
        float r2 = (t2 - e2) * mr;
        float g0 = e0 * md;
        float g1 = e1 * md;
        float g2 = e2 * mr;
        num += (double)r0 * r0 + (double)r1 * r1 + (double)r2 * r2;
        den += (double)g0 * g0 + (double)g1 * g1 + (double)g2 * g2;
    }
    #pragma unroll
    for (int off = 32; off > 0; off >>= 1) {
        num += __shfl_down(num, off, 64);
        den += __shfl_down(den, off, 64);
    }
    if (lane == 0) { sn[wv] = num; sd[wv] = den; }
    __syncthreads();
    if (tid == 0) {
        double tn = 0.0, td = 0.0;
        #pragma unroll
        for (int w = 0; w < 16; ++w) { tn += sn[w]; td += sd[w]; }
        double* slot = accSlots + (size_t)(b & 63) * 8;
        atomicAdd(&slot[0], tn);
        atomicAdd(&slot[1], td);
    }
}

__global__ void final_kernel(const double* __restrict__ accSlots,
                             float* __restrict__ out) {
    int t = threadIdx.x;   // 64 threads
    double n = accSlots[t * 8 + 0];
    double d = accSlots[t * 8 + 1];
    #pragma unroll
    for (int off = 32; off > 0; off >>= 1) {
        n += __shfl_down(n, off, 64);
        d += __shfl_down(d, off, 64);
    }
    if (t == 0) {
        if (d < 1e-30) d = 1e-30;
        out[0] = (float)(n / d);
    }
}

static inline size_t align256(size_t x) { return (x + 255) & ~(size_t)255; }

extern "C" void kernel_launch(void* const* d_in, const int* in_sizes, int n_in,
                              void* d_out, int out_size, void* d_ws, size_t ws_size,
                              hipStream_t stream) {
    const float* pred    = (const float*)d_in[0];
    const float* u_c     = (const float*)d_in[1];
    const float* theta_c = (const float*)d_in[2];
    const float* len     = (const float*)d_in[3];
    const float* pE      = (const float*)d_in[4];
    const float* pA      = (const float*)d_in[5];
    const float* pI      = (const float*)d_in[6];
    const float* dir     = (const float*)d_in[7];
    const float* Fext    = (const float*)d_in[8];
    const float* bcd     = (const float*)d_in[9];
    const float* bcr     = (const float*)d_in[10];
    const long long* conn = (const long long*)d_in[11];

    int N = in_sizes[0] / 3;
    int E = in_sizes[3];
    int NBc = (N + SPANC - 1) / SPANC;   // coarse buckets, must be <= NBC

    // Workspace layout:
    //   0      accSlots   4096 B (64 slots * 64B)
    //   4096   cursors    NBC*CURP*4 = 16384 B
    //   20480  base       (NBC+1)*4 B
    //   21760  upack      8*N B (fp16x3+pad per node, ALWAYS present)
    //   oFint  fp16/int32 partial F_int (K>1 only)
    //   oArena arena: 2*chunkElems records * 8 B; count-row matrix
    //          rows[CB][NBC] (96 KB) aliases the arena head (consumed by
    //          scan before fill writes).
    size_t oCur   = 4096;
    size_t oBase  = oCur + (size_t)NBC * CURP * 4;           // 20480
    size_t oU     = align256(oBase + 4 * (NBC + 1));         // 21760
    size_t upB    = (size_t)N * 8;
    size_t oFint0 = align256(oU + upB);
    size_t rowsBytes = (size_t)CB * NBC * 4;                 // 98304

    // Ladder (all rungs use upack): K chunks, partial mode (0 none/1 int32/2 fp16)
    const int cfgK[6] = {1, 2, 3, 4, 6, 8};
    const int cfgM[6] = {0, 2, 2, 2, 2, 2};
    int K = 8, mode = 2;
    size_t oF = oFint0, oA = oFint0;
    for (int t = 0; t < 6; ++t) {
        int Kc = cfgK[t], Mc = cfgM[t];
        size_t chunkE = (size_t)(E + Kc - 1) / Kc;
        size_t fsz = (Kc > 1) ? (size_t)3 * N * (Mc == 1 ? 4 : 2) : 0;
        size_t oAt = align256(oFint0 + fsz);
        size_t arenaB = 2 * chunkE * 8;
        if (arenaB < rowsBytes) arenaB = rowsBytes;   // alias safety for tiny E
        size_t need = oAt + arenaB;
        if (need <= ws_size || t == 5) {
            K = Kc; mode = Mc; oF = oFint0; oA = oAt;
            if (need <= ws_size) break;
        }
    }

    int chunkElems = (E + K - 1) / K;

    double*             accSlots = (double*)d_ws;
    int*                cursor   = (int*)((char*)d_ws + oCur);
    int*                base     = (int*)((char*)d_ws + oBase);
    uint2*              upk      = (uint2*)((char*)d_ws + oU);
    int*                fintI    = (int*)((char*)d_ws + oF);
    unsigned short*     fint16   = (unsigned short*)((char*)d_ws + oF);
    uint2*              arena    = (uint2*)((char*)d_ws + oA);
    unsigned long long* arenaLL  = (unsigned long long*)arena;
    int*                rows     = (int*)arena;       // alias, pre-fill only

    upack_kernel<<<(N + 1023) / 1024, 1024, 0, stream>>>(pred, u_c, theta_c, upk, N);

    for (int c = 0; c < K; ++c) {
        int cs = c * chunkElems;
        if (cs >= E) break;
        int ce = cs + chunkElems;
        if (ce > E) ce = E;
        int NT = (ce - cs + FBE - 1) / FBE;

        int isFirst = (c == 0);
        int isLast  = (ce == E);

        count_kernel<<<CB, 1024, 0, stream>>>(conn, rows, cs, ce);
        scan_kernel<<<1, 1024, 0, stream>>>(rows, cursor, base, accSlots, isFirst);
        fill_kernel<<<NT, FTH, 0, stream>>>(
            conn, upk, len, pE, pA, pI, dir, arena, cursor, cs, ce);
        accum_kernel<<<NBc, ATH, 0, stream>>>(
            arenaLL, base, Fext, bcd, bcr, accSlots,
            fintI, fint16, N, isFirst, isLast, mode);
    }

    final_kernel<<<1, 64, 0, stream>>>(accSlots, (float*)d_out);
}